// Round 12
// baseline (72.897 us; speedup 1.0000x reference)
//
#include <hip/hip_runtime.h>
#include <math.h>

#define NROWS 8192
#define NK    4096
#define NE    64
#define NCH   32     // K chunks of 128

typedef _Float16 f16x8 __attribute__((ext_vector_type(8)));  // 4 VGPRs
typedef float    f32x4 __attribute__((ext_vector_type(4)));

// f32 -> (hi,lo) f16 pair, elementwise for 8 values in two float4s
#define CVT8(H, L, V0, V1)                                            \
  do {                                                                \
    H[0] = (_Float16)V0.x; L[0] = (_Float16)(V0.x - (float)H[0]);     \
    H[1] = (_Float16)V0.y; L[1] = (_Float16)(V0.y - (float)H[1]);     \
    H[2] = (_Float16)V0.z; L[2] = (_Float16)(V0.z - (float)H[2]);     \
    H[3] = (_Float16)V0.w; L[3] = (_Float16)(V0.w - (float)H[3]);     \
    H[4] = (_Float16)V1.x; L[4] = (_Float16)(V1.x - (float)H[4]);     \
    H[5] = (_Float16)V1.y; L[5] = (_Float16)(V1.y - (float)H[5]);     \
    H[6] = (_Float16)V1.z; L[6] = (_Float16)(V1.z - (float)H[6]);     \
    H[7] = (_Float16)V1.w; L[7] = (_Float16)(V1.w - (float)H[7]);     \
  } while (0)

// async global -> LDS, 16B/lane: LDS dest = wave-uniform base + lane*16 (m104);
// global source is per-lane (m173). Worked (absmax 0) in round 10.
__device__ __forceinline__ void gload16(const void* g, void* l) {
  __builtin_amdgcn_global_load_lds(
      (const __attribute__((address_space(1))) unsigned int*)g,
      (__attribute__((address_space(3))) unsigned int*)l, 16, 0, 0);
}

// ---------------------------------------------------------------------------
// Kernel 0: W -> MFMA-fragment-linear f16 hi/lo (verified rounds 4-11) and
// zero imp + block counter. Element ((ksg*4 + nt)*64 + lane)*8 + j holds
//   f16( W[nt*16 + (lane&15)][ksg*32 + (lane>>4)*8 + j] ), ksg = 0..127.
// Chunk c (BK=128) = ksg c*4..c*4+3 -> 8192 f16 contiguous per chunk.
// ---------------------------------------------------------------------------
__global__ __launch_bounds__(256) void k_prep(const float* __restrict__ W,
                                              _Float16* __restrict__ Whi,
                                              _Float16* __restrict__ Wlo,
                                              float* __restrict__ imp,
                                              unsigned* __restrict__ cnt) {
  const int idx = blockIdx.x * 256 + threadIdx.x;   // 0 .. 262143
  if (idx < NE) imp[idx] = 0.f;
  if (idx == NE) *cnt = 0u;
  const int j    = idx & 7;
  const int lane = (idx >> 3) & 63;
  const int nt   = (idx >> 9) & 3;
  const int ksg  = idx >> 11;                        // 0..127
  const int e = nt * 16 + (lane & 15);
  const int k = ksg * 32 + (lane >> 4) * 8 + j;
  const float w = W[(size_t)e * NK + k];
  const _Float16 wh = (_Float16)w;
  const _Float16 wl = (_Float16)(w - (float)wh);
  Whi[idx] = wh;
  Wlo[idx] = wl;
}

// ---------------------------------------------------------------------------
// Kernel 1 (FUSED): 32 rows x full K per block; x AND W staged via
// global_load_lds (no VGPR staging -> allocator cannot serialize it; rounds
// 6-11 showed register staging caps in-flight bytes at ~1/3 of the BDP).
// grid = 256 (1 block/CU), block = 256 (4 waves: wave (mi,ni) = 16 rows x 32
// experts). 32 chunks of BK=128, double-buffered, counted vmcnt(12) (T4):
// next stage's 12 loads stay in flight across barriers -> ~48 KB/CU
// outstanding >> 22 KB BDP -> HBM-saturating.
// x LDS tile [32][128] f32: source pre-swizzled u^=(row&7) (16B units, rule
// 21 both-sides) -> conflict-spread b128 reads. W tiles: fragment-linear =
// lane-linear, naturally conflict-free.
// Epilogue: verified softmax/top-2/renorm + importance + last-block aux.
// ---------------------------------------------------------------------------
__global__ __launch_bounds__(256) void k_fused(const float* __restrict__ x,
                                               const _Float16* __restrict__ Whi,
                                               const _Float16* __restrict__ Wlo,
                                               float* __restrict__ out,
                                               float* __restrict__ imp,
                                               unsigned* __restrict__ cnt) {
  __shared__ float Xs[2][32][128];    // 32 KB x tiles (swizzled 16B units)
  __shared__ f16x8 WHs[2][16][64];    // 32 KB W hi frags [ks*4+ntg][lane]
  __shared__ f16x8 WLs[2][16][64];    // 32 KB W lo frags
  __shared__ int lastflag;

  const int tid  = threadIdx.x;
  const int lane = tid & 63;
  const int wv   = __builtin_amdgcn_readfirstlane(tid >> 6);  // 0..3
  const int mi   = wv >> 1;            // row half (0..1)
  const int ni   = wv & 1;             // expert half (0..1)
  const int l15  = lane & 15;
  const int lhi  = lane >> 4;
  const int rb   = blockIdx.x * 32;
  const int myrow = mi * 16 + l15;     // 0..31 row in tile
  const int r7    = l15 & 7;           // swizzle key for my row

  // stage chunk cc into buffer bb: 4 x-units + 4 WH + 4 WL per thread = 12
#define STAGE(cc, bb)                                                         \
  do {                                                                        \
    const int koff = (cc) * 128;                                              \
    const size_t wbase = (size_t)(cc) * 8192; /* f16 per chunk */             \
    _Pragma("unroll")                                                         \
    for (int i = 0; i < 4; ++i) {                                             \
      const int t = tid + i * 256;     /* 16B unit 0..1023 */                 \
      const int row = t >> 5, u = t & 31;                                     \
      const float* gs = x + (size_t)(rb + row) * NK + koff +                  \
                        ((u ^ (row & 7)) << 2);                               \
      const int du = wv * 1024 + i * 4096; /* wave-uniform dest offset */     \
      gload16(gs, (char*)&Xs[bb][0][0] + du);                                 \
      gload16(Whi + wbase + (size_t)t * 8, (char*)&WHs[bb][0][0] + du);       \
      gload16(Wlo + wbase + (size_t)t * 8, (char*)&WLs[bb][0][0] + du);       \
    }                                                                         \
  } while (0)

#define COMPUTE(bb)                                                           \
  do {                                                                        \
    _Pragma("unroll")                                                         \
    for (int ks = 0; ks < 4; ++ks) {                                          \
      const int c0 = ks * 8 + lhi * 2;                                        \
      const float4 xa =                                                       \
          *(const float4*)&Xs[bb][myrow][((c0 ^ r7) << 2)];                   \
      const float4 xc =                                                       \
          *(const float4*)&Xs[bb][myrow][(((c0 + 1) ^ r7) << 2)];             \
      f16x8 ah, al;                                                           \
      CVT8(ah, al, xa, xc);                                                   \
      _Pragma("unroll")                                                       \
      for (int nt = 0; nt < 2; ++nt) {                                        \
        const f16x8 wh = WHs[bb][ks * 4 + ni * 2 + nt][lane];                 \
        const f16x8 wl = WLs[bb][ks * 4 + ni * 2 + nt][lane];                 \
        accp[nt] = __builtin_amdgcn_mfma_f32_16x16x32_f16(ah, wh, accp[nt], 0, 0, 0); \
        accq[nt] = __builtin_amdgcn_mfma_f32_16x16x32_f16(ah, wl, accq[nt], 0, 0, 0); \
        accq[nt] = __builtin_amdgcn_mfma_f32_16x16x32_f16(al, wh, accq[nt], 0, 0, 0); \
      }                                                                       \
    }                                                                         \
  } while (0)

  f32x4 accp[2], accq[2];
#pragma unroll
  for (int nt = 0; nt < 2; ++nt) {
    accp[nt] = (f32x4){0.f, 0.f, 0.f, 0.f};
    accq[nt] = (f32x4){0.f, 0.f, 0.f, 0.f};
  }

  STAGE(0, 0);
  STAGE(1, 1);

#pragma unroll 1
  for (int c = 0; c < NCH - 1; ++c) {
    asm volatile("s_waitcnt vmcnt(12)" ::: "memory");  // stage(c) done; (c+1) in flight
    __builtin_amdgcn_sched_barrier(0);
    __builtin_amdgcn_s_barrier();                      // raw: no drain
    __builtin_amdgcn_sched_barrier(0);
    COMPUTE(c & 1);
    __builtin_amdgcn_s_barrier();                      // all reads of buf[c&1] done
    __builtin_amdgcn_sched_barrier(0);
    if (c < NCH - 2) STAGE(c + 2, c & 1);
  }
  asm volatile("s_waitcnt vmcnt(0)" ::: "memory");
  __builtin_amdgcn_sched_barrier(0);
  __builtin_amdgcn_s_barrier();
  __builtin_amdgcn_sched_barrier(0);
  COMPUTE((NCH - 1) & 1);
  __syncthreads();

  // ---- logits to LDS (overlay on Xs buf0; compute read buf1 last) ----
  float* logitp = &Xs[0][0][0];        // [32][64]
  float* simpp  = (float*)&WHs[0][0][0];
#pragma unroll
  for (int nt = 0; nt < 2; ++nt) {
    const f32x4 accf = accp[nt] + accq[nt];
#pragma unroll
    for (int r = 0; r < 4; ++r)
      logitp[(mi * 16 + lhi * 4 + r) * 64 + ni * 32 + nt * 16 + l15] = accf[r];
  }
  __syncthreads();

  // ---- softmax/top-2/renorm (verified rounds 5-11): wave wv rows wv*8..+8 --
  float impacc = 0.f;
#pragma unroll 1
  for (int i = 0; i < 8; ++i) {
    const int rl  = wv * 8 + i;
    const int row = rb + rl;
    const float lg = logitp[rl * 64 + lane];

    float m = lg;
#pragma unroll
    for (int d = 1; d < 64; d <<= 1) m = fmaxf(m, __shfl_xor(m, d));
    float p = expf(lg - m);
    float s = p;
#pragma unroll
    for (int d = 1; d < 64; d <<= 1) s += __shfl_xor(s, d);
    const float gate = p / s;
    impacc += gate;

    const unsigned long long key =
        ((unsigned long long)__float_as_uint(gate) << 32) | (unsigned)(63 - lane);
    unsigned long long k1 = key;
#pragma unroll
    for (int d = 1; d < 64; d <<= 1) {
      unsigned long long o = __shfl_xor(k1, d);
      if (o > k1) k1 = o;
    }
    const int e1 = 63 - (int)(k1 & 63ull);
    unsigned long long k2 = (lane == e1) ? 0ull : key;
#pragma unroll
    for (int d = 1; d < 64; d <<= 1) {
      unsigned long long o = __shfl_xor(k2, d);
      if (o > k2) k2 = o;
    }
    const int e2 = 63 - (int)(k2 & 63ull);

    if (lane == 0) {
      const float g1 = __uint_as_float((unsigned)(k1 >> 32));
      const float g2 = __uint_as_float((unsigned)(k2 >> 32));
      const float tt  = expf(g2 - g1);          // g1 >= g2
      const float inv = 1.f / (1.f + tt);
      out[(size_t)row * 2]     = inv;
      out[(size_t)row * 2 + 1] = tt * inv;
      out[(size_t)NROWS * 2 + row * 2]     = (float)e1;
      out[(size_t)NROWS * 2 + row * 2 + 1] = (float)e2;
    }
  }
  simpp[wv * 64 + lane] = impacc;
  __syncthreads();

  // ---- importance atomics + last-block aux (verified rounds 7/11) ----
  if (tid < NE) {
    const float v = (simpp[0 * 64 + tid] + simpp[1 * 64 + tid]) +
                    (simpp[2 * 64 + tid] + simpp[3 * 64 + tid]);
    atomicAdd(&imp[tid], v);
  }
  __syncthreads();

  if (tid == 0) {
    const unsigned old = atomicAdd(cnt, 1u);
    lastflag = (old == 255u) ? 1 : 0;
  }
  __syncthreads();

  if (lastflag && tid < NE) {
    const float v = atomicAdd(&imp[tid], 0.f);   // device-scope read
    float s = v;
#pragma unroll
    for (int d = 1; d < 64; d <<= 1) s += __shfl_xor(s, d);
    const float mean = s / 64.f;
    const float dv = v - mean;
    float sq = dv * dv;
#pragma unroll
    for (int d = 1; d < 64; d <<= 1) sq += __shfl_xor(sq, d);
    const float stdv = sqrtf(sq / 63.f);  // unbiased (E-1)
    const float r = stdv / (mean + 1e-6f);
    if (tid == 0) out[(size_t)NROWS * 4] = r * r;  // d_out[32768]
  }
}

// ---------------------------------------------------------------------------
extern "C" void kernel_launch(void* const* d_in, const int* in_sizes, int n_in,
                              void* d_out, int out_size, void* d_ws, size_t ws_size,
                              hipStream_t stream) {
  const float* x = (const float*)d_in[0];
  const float* W = (const float*)d_in[1];
  float* out  = (float*)d_out;
  _Float16* Whi = (_Float16*)d_ws;                 // 512 KB
  _Float16* Wlo = Whi + (size_t)NE * NK;           // 512 KB
  float* imp  = (float*)(Wlo + (size_t)NE * NK);   // 64 f32
  unsigned* cnt = (unsigned*)(imp + NE);           // 1 u32

  hipLaunchKernelGGL(k_prep,  dim3(1024), dim3(256), 0, stream, W, Whi, Wlo, imp, cnt);
  hipLaunchKernelGGL(k_fused, dim3(256),  dim3(256), 0, stream, x, Whi, Wlo, out, imp, cnt);
}

// Round 14
// 67.179 us; speedup vs baseline: 1.0851x; 1.0851x over previous
//
#include <hip/hip_runtime.h>
#include <math.h>

#define NROWS 8192
#define NK    4096
#define NE    64
#define NCH   32     // K chunks of 128

typedef _Float16 f16x8 __attribute__((ext_vector_type(8)));  // 4 VGPRs
typedef float    f32x4 __attribute__((ext_vector_type(4)));

// f32 -> (hi,lo) f16 pair, elementwise for 8 values in two float4s
#define CVT8(H, L, V0, V1)                                            \
  do {                                                                \
    H[0] = (_Float16)V0.x; L[0] = (_Float16)(V0.x - (float)H[0]);     \
    H[1] = (_Float16)V0.y; L[1] = (_Float16)(V0.y - (float)H[1]);     \
    H[2] = (_Float16)V0.z; L[2] = (_Float16)(V0.z - (float)H[2]);     \
    H[3] = (_Float16)V0.w; L[3] = (_Float16)(V0.w - (float)H[3]);     \
    H[4] = (_Float16)V1.x; L[4] = (_Float16)(V1.x - (float)H[4]);     \
    H[5] = (_Float16)V1.y; L[5] = (_Float16)(V1.y - (float)H[5]);     \
    H[6] = (_Float16)V1.z; L[6] = (_Float16)(V1.z - (float)H[6]);     \
    H[7] = (_Float16)V1.w; L[7] = (_Float16)(V1.w - (float)H[7]);     \
  } while (0)

// async global -> LDS: LDS dest = wave-uniform base + lane*16 (m104); global
// source per-lane (m173). Data-verified rounds 10/12 (absmax 0).
__device__ __forceinline__ void gload16(const void* g, void* l) {
  __builtin_amdgcn_global_load_lds(
      (const __attribute__((address_space(1))) unsigned int*)g,
      (__attribute__((address_space(3))) unsigned int*)l, 16, 0, 0);
}

// ---------------------------------------------------------------------------
// Kernel 0: W -> MFMA-fragment-linear f16 hi/lo (verified rounds 4-12); zero
// imp + completion counter. Element ((ksg*4 + nt)*64 + lane)*8 + j holds
//   f16( W[nt*16 + (lane&15)][ksg*32 + (lane>>4)*8 + j] ), ksg = 0..127.
// Chunk c (BK=128) = ksg c*4..c*4+3 -> base c*8192 f16, 8192 f16 per chunk.
// ---------------------------------------------------------------------------
__global__ __launch_bounds__(256) void k_prep(const float* __restrict__ W,
                                              _Float16* __restrict__ Whi,
                                              _Float16* __restrict__ Wlo,
                                              float* __restrict__ imp,
                                              unsigned* __restrict__ cnt) {
  const int idx = blockIdx.x * 256 + threadIdx.x;   // 0 .. 262143
  if (idx < NE) imp[idx] = 0.f;
  if (idx == NE) *cnt = 0u;
  const int j    = idx & 7;
  const int lane = (idx >> 3) & 63;
  const int nt   = (idx >> 9) & 3;
  const int ksg  = idx >> 11;                        // 0..127
  const int e = nt * 16 + (lane & 15);
  const int k = ksg * 32 + (lane >> 4) * 8 + j;
  const float w = W[(size_t)e * NK + k];
  const _Float16 wh = (_Float16)w;
  const _Float16 wl = (_Float16)(w - (float)wh);
  Whi[idx] = wh;
  Wlo[idx] = wl;
}

// ---------------------------------------------------------------------------
// Kernel 1 (FUSED, m97-shape): 32 rows x full K per block; x AND W staged by
// global_load_lds in FRAGMENT-LINEAR layout (every ds_read is lane-linear
// 16B -> zero bank conflicts), double-buffered with ONE __syncthreads per
// chunk (drains ALL waves' vmcnt -> r12's cross-wave vmcnt race impossible).
// ROUND-14 FIX: W chunk base = c*8192 f16 (r13 used c*16384 — factor 2 —
// so chunks >= 16 read Wlo as hi-fragments: garbage logits, indices off).
// grid = 256 (1 block/CU), block = 512 (8 waves; wave (mi,ni) = 16 rows x 16
// experts, acc = 2 x f32x4). Per-chunk VMEM = 6 gload16/thread (no VGPR dest).
// ---------------------------------------------------------------------------
__global__ __launch_bounds__(512) void k_fused(const float* __restrict__ x,
                                               const _Float16* __restrict__ Whi,
                                               const _Float16* __restrict__ Wlo,
                                               float* __restrict__ out,
                                               float* __restrict__ imp,
                                               unsigned* __restrict__ cnt) {
  __shared__ float4 XA[2][4][2][2][64];  // 32 KB [buf][ks][mi][half][lane]
  __shared__ f16x8  WH[2][4][4][64];     // 32 KB [buf][ks][nt][lane]
  __shared__ f16x8  WL[2][4][4][64];     // 32 KB
  __shared__ int lastflag;

  const int tid  = threadIdx.x;
  const int lane = tid & 63;
  const int wv   = __builtin_amdgcn_readfirstlane(tid >> 6);  // 0..7
  const int mi   = wv >> 2;            // row half (0..1)
  const int ni   = wv & 3;             // expert quarter (0..3)
  const int l15  = lane & 15;
  const int lhi  = lane >> 4;
  const int rb   = blockIdx.x * 32;

  // x source for this thread's 2 XA units (unit t = a*512 + tid):
  //   ks = t>>8 ; mi_s = (t>>7)&1 ; half = (t>>6)&1 ; dest lane = t&63 = lane
  //   row = mi_s*16 + (lane&15) ; k = ks*32 + (lane>>4)*8 + half*4
  const int t0   = tid;                // a = 0
  const int t1   = 512 + tid;          // a = 1
  const int xrow0 = ((t0 >> 7) & 1) * 16 + l15;
  const int xrow1 = ((t1 >> 7) & 1) * 16 + l15;
  const int xk0   = (t0 >> 8) * 32 + lhi * 8 + ((t0 >> 6) & 1) * 4;
  const int xk1   = (t1 >> 8) * 32 + lhi * 8 + ((t1 >> 6) & 1) * 4;
  const float* __restrict__ xs0 = x + (size_t)(rb + xrow0) * NK + xk0;
  const float* __restrict__ xs1 = x + (size_t)(rb + xrow1) * NK + xk1;
  // wave-uniform LDS dest byte offsets (unit t lands at flat byte t*16)
  const int du0 = (wv * 64) * 16;            // a = 0
  const int du1 = (512 + wv * 64) * 16;      // a = 1

#define STAGE(cc, bb)                                                         \
  do {                                                                        \
    const int koff = (cc) * 128;                                              \
    const size_t wb = (size_t)(cc) * 8192;  /* f16 per chunk = 1024 units */  \
    gload16(xs0 + koff, (char*)&XA[bb][0][0][0][0] + du0);                    \
    gload16(xs1 + koff, (char*)&XA[bb][0][0][0][0] + du1);                    \
    gload16(Whi + wb + (size_t)(t0) * 8, (char*)&WH[bb][0][0][0] + du0);      \
    gload16(Whi + wb + (size_t)(t1) * 8, (char*)&WH[bb][0][0][0] + du1);      \
    gload16(Wlo + wb + (size_t)(t0) * 8, (char*)&WL[bb][0][0][0] + du0);      \
    gload16(Wlo + wb + (size_t)(t1) * 8, (char*)&WL[bb][0][0][0] + du1);      \
  } while (0)

#define COMPUTE(bb)                                                           \
  do {                                                                        \
    _Pragma("unroll")                                                         \
    for (int ks = 0; ks < 4; ++ks) {                                          \
      const float4 xa = XA[bb][ks][mi][0][lane];                              \
      const float4 xc = XA[bb][ks][mi][1][lane];                              \
      const f16x8 wh = WH[bb][ks][ni][lane];                                  \
      const f16x8 wl = WL[bb][ks][ni][lane];                                  \
      f16x8 ah, al;                                                           \
      CVT8(ah, al, xa, xc);                                                   \
      accp = __builtin_amdgcn_mfma_f32_16x16x32_f16(ah, wh, accp, 0, 0, 0);   \
      accq = __builtin_amdgcn_mfma_f32_16x16x32_f16(ah, wl, accq, 0, 0, 0);   \
      accq = __builtin_amdgcn_mfma_f32_16x16x32_f16(al, wh, accq, 0, 0, 0);   \
    }                                                                         \
  } while (0)

  f32x4 accp = (f32x4){0.f, 0.f, 0.f, 0.f};
  f32x4 accq = (f32x4){0.f, 0.f, 0.f, 0.f};

  STAGE(0, 0);
  __syncthreads();                     // chunk 0 resident

#pragma unroll 1
  for (int c = 0; c < NCH; ++c) {
    if (c + 1 < NCH) STAGE(c + 1, (c + 1) & 1);  // async into other buffer
    COMPUTE(c & 1);
    __syncthreads();                   // drains vmcnt(0): stage(c+1) resident,
                                       // buf(c) reads complete (m97 shape)
  }

  // ---- logits to LDS overlay -> softmax/top-2/renorm (verified r6-r12) ----
  float* logitp = (float*)&XA[0][0][0][0][0];   // [32][64]
  float* simpp  = (float*)&WH[0][0][0][0];      // [8][64]
  {
    const f32x4 accf = accp + accq;
#pragma unroll
    for (int r = 0; r < 4; ++r)
      logitp[(mi * 16 + lhi * 4 + r) * 64 + ni * 16 + l15] = accf[r];
  }
  __syncthreads();

  float impacc = 0.f;
#pragma unroll 1
  for (int i = 0; i < 4; ++i) {
    const int rl  = wv * 4 + i;
    const int row = rb + rl;
    const float lg = logitp[rl * 64 + lane];

    float m = lg;
#pragma unroll
    for (int d = 1; d < 64; d <<= 1) m = fmaxf(m, __shfl_xor(m, d));
    float p = expf(lg - m);
    float s = p;
#pragma unroll
    for (int d = 1; d < 64; d <<= 1) s += __shfl_xor(s, d);
    const float gate = p / s;
    impacc += gate;

    const unsigned long long key =
        ((unsigned long long)__float_as_uint(gate) << 32) | (unsigned)(63 - lane);
    unsigned long long k1 = key;
#pragma unroll
    for (int d = 1; d < 64; d <<= 1) {
      unsigned long long o = __shfl_xor(k1, d);
      if (o > k1) k1 = o;
    }
    const int e1 = 63 - (int)(k1 & 63ull);
    unsigned long long k2 = (lane == e1) ? 0ull : key;
#pragma unroll
    for (int d = 1; d < 64; d <<= 1) {
      unsigned long long o = __shfl_xor(k2, d);
      if (o > k2) k2 = o;
    }
    const int e2 = 63 - (int)(k2 & 63ull);

    if (lane == 0) {
      const float g1 = __uint_as_float((unsigned)(k1 >> 32));
      const float g2 = __uint_as_float((unsigned)(k2 >> 32));
      const float tt  = expf(g2 - g1);          // g1 >= g2
      const float inv = 1.f / (1.f + tt);
      out[(size_t)row * 2]     = inv;
      out[(size_t)row * 2 + 1] = tt * inv;
      out[(size_t)NROWS * 2 + row * 2]     = (float)e1;
      out[(size_t)NROWS * 2 + row * 2 + 1] = (float)e2;
    }
  }
  simpp[wv * 64 + lane] = impacc;
  __syncthreads();

  // ---- importance atomics + last-block aux (verified rounds 7/11/12) ----
  if (tid < NE) {
    const float v =
        (((simpp[0 * 64 + tid] + simpp[1 * 64 + tid]) +
          (simpp[2 * 64 + tid] + simpp[3 * 64 + tid])) +
         ((simpp[4 * 64 + tid] + simpp[5 * 64 + tid]) +
          (simpp[6 * 64 + tid] + simpp[7 * 64 + tid])));
    atomicAdd(&imp[tid], v);
  }
  __syncthreads();

  if (tid == 0) {
    const unsigned old = atomicAdd(cnt, 1u);
    lastflag = (old == 255u) ? 1 : 0;
  }
  __syncthreads();

  if (lastflag && tid < NE) {
    const float v = atomicAdd(&imp[tid], 0.f);   // device-scope read
    float s = v;
#pragma unroll
    for (int d = 1; d < 64; d <<= 1) s += __shfl_xor(s, d);
    const float mean = s / 64.f;
    const float dv = v - mean;
    float sq = dv * dv;
#pragma unroll
    for (int d = 1; d < 64; d <<= 1) sq += __shfl_xor(sq, d);
    const float stdv = sqrtf(sq / 63.f);  // unbiased (E-1)
    const float r = stdv / (mean + 1e-6f);
    if (tid == 0) out[(size_t)NROWS * 4] = r * r;  // d_out[32768]
  }
}

// ---------------------------------------------------------------------------
extern "C" void kernel_launch(void* const* d_in, const int* in_sizes, int n_in,
                              void* d_out, int out_size, void* d_ws, size_t ws_size,
                              hipStream_t stream) {
  const float* x = (const float*)d_in[0];
  const float* W = (const float*)d_in[1];
  float* out  = (float*)d_out;
  _Float16* Whi = (_Float16*)d_ws;                 // 512 KB
  _Float16* Wlo = Whi + (size_t)NE * NK;           // 512 KB
  float* imp  = (float*)(Wlo + (size_t)NE * NK);   // 64 f32
  unsigned* cnt = (unsigned*)(imp + NE);           // 1 u32

  hipLaunchKernelGGL(k_prep,  dim3(1024), dim3(256), 0, stream, W, Whi, Wlo, imp, cnt);
  hipLaunchKernelGGL(k_fused, dim3(256),  dim3(512), 0, stream, x, Whi, Wlo, out, imp, cnt);
}

// Round 15
// 49.658 us; speedup vs baseline: 1.4680x; 1.3528x over previous
//
#include <hip/hip_runtime.h>
#include <math.h>

#define NROWS 8192
#define NK    4096
#define NE    64
#define NWV   8     // waves per block = K segments of 512

typedef _Float16 f16x8 __attribute__((ext_vector_type(8)));  // 4 VGPRs
typedef float    f32x4 __attribute__((ext_vector_type(4)));

// f32 -> (hi,lo) f16 pair, elementwise for 8 values in two float4s
#define CVT8(H, L, V0, V1)                                            \
  do {                                                                \
    H[0] = (_Float16)V0.x; L[0] = (_Float16)(V0.x - (float)H[0]);     \
    H[1] = (_Float16)V0.y; L[1] = (_Float16)(V0.y - (float)H[1]);     \
    H[2] = (_Float16)V0.z; L[2] = (_Float16)(V0.z - (float)H[2]);     \
    H[3] = (_Float16)V0.w; L[3] = (_Float16)(V0.w - (float)H[3]);     \
    H[4] = (_Float16)V1.x; L[4] = (_Float16)(V1.x - (float)H[4]);     \
    H[5] = (_Float16)V1.y; L[5] = (_Float16)(V1.y - (float)H[5]);     \
    H[6] = (_Float16)V1.z; L[6] = (_Float16)(V1.z - (float)H[6]);     \
    H[7] = (_Float16)V1.w; L[7] = (_Float16)(V1.w - (float)H[7]);     \
  } while (0)

// ---------------------------------------------------------------------------
// Kernel 0: W -> MFMA-fragment-linear f16 hi/lo (verified rounds 4-14); zero
// imp + completion counter. Element ((ksg*4 + nt)*64 + lane)*8 + j holds
//   f16( W[nt*16 + (lane&15)][ksg*32 + (lane>>4)*8 + j] ), ksg = 0..127.
// ---------------------------------------------------------------------------
__global__ __launch_bounds__(256) void k_prep(const float* __restrict__ W,
                                              _Float16* __restrict__ Whi,
                                              _Float16* __restrict__ Wlo,
                                              float* __restrict__ imp,
                                              unsigned* __restrict__ cnt) {
  const int idx = blockIdx.x * 256 + threadIdx.x;   // 0 .. 262143
  if (idx < NE) imp[idx] = 0.f;
  if (idx == NE) *cnt = 0u;
  const int j    = idx & 7;
  const int lane = (idx >> 3) & 63;
  const int nt   = (idx >> 9) & 3;
  const int ksg  = idx >> 11;                        // 0..127
  const int e = nt * 16 + (lane & 15);
  const int k = ksg * 32 + (lane >> 4) * 8 + j;
  const float w = W[(size_t)e * NK + k];
  const _Float16 wh = (_Float16)w;
  const _Float16 wl = (_Float16)(w - (float)wh);
  Whi[idx] = wh;
  Wlo[idx] = wl;
}

// ---------------------------------------------------------------------------
// Kernel 1 (FUSED, r9 structure + PINNED prefetch): 32 rows x full K per
// block; grid = 256 (1 block/CU), block = 512 (8 waves, wave wv = K-seg 512,
// two 16-row M-tiles sharing B-frags -> bit-identical math to rounds 6/9).
// ROUND-15 KEY CHANGE: per k-step, [issue W(ks+1) + x(ks+2) loads] ->
// sched_barrier(0) -> [compute ks] -> sched_barrier(0). The fence makes it
// impossible for the scheduler to sink prefetches to their uses (r8/r9
// showed it does exactly that at VGPR<=88, leaving ~4 loads in flight vs the
// ~16 the BDP needs). With pinned order the auto-waitcnt before the first
// MFMA is vmcnt(16): 16 KB/wave in flight, 8 waves/CU = 128 KB >> 22 KB BDP.
// Last block computes aux (verified counter pattern, rounds 12/14).
// ---------------------------------------------------------------------------
__global__ __launch_bounds__(512)
__attribute__((amdgpu_waves_per_eu(2, 2)))
void k_fused(const float* __restrict__ x,
             const _Float16* __restrict__ Whi,
             const _Float16* __restrict__ Wlo,
             float* __restrict__ out,
             float* __restrict__ imp,
             unsigned* __restrict__ cnt) {
  __shared__ float plds[NWV][32][64];   // 64 KB partial logits
  __shared__ float logit[32][64];       // 8 KB reduced logits
  __shared__ float simp[NWV][64];       // 2 KB importance partials
  __shared__ int lastflag;

  const int tid  = threadIdx.x;
  const int lane = tid & 63;
  const int wv   = __builtin_amdgcn_readfirstlane(tid >> 6);  // 0..7 = K-seg
  const int l15  = lane & 15;
  const int lhi  = lane >> 4;
  const int rbase = blockIdx.x * 32;
  const int k0    = wv * 512;

  const float* __restrict__ xp0 = x + (size_t)(rbase + l15) * NK + k0 + lhi * 8;
  const float* __restrict__ xp1 = xp0 + (size_t)16 * NK;
  const _Float16* __restrict__ whp = Whi + ((size_t)(wv * 16 * 4) * 64 + lane) * 8;
  const _Float16* __restrict__ wlp = Wlo + ((size_t)(wv * 16 * 4) * 64 + lane) * 8;

  f32x4 acc0[4], acc1[4];
#pragma unroll
  for (int nt = 0; nt < 4; ++nt) {
    acc0[nt] = (f32x4){0.f, 0.f, 0.f, 0.f};
    acc1[nt] = (f32x4){0.f, 0.f, 0.f, 0.f};
  }

  // ---- prologue: x for ks=0,1 and W-frags for ks=0 ----
  float4 ca0 = *(const float4*)(xp0);
  float4 ca1 = *(const float4*)(xp0 + 4);
  float4 cb0 = *(const float4*)(xp1);
  float4 cb1 = *(const float4*)(xp1 + 4);
  float4 na0 = *(const float4*)(xp0 + 32);
  float4 na1 = *(const float4*)(xp0 + 36);
  float4 nb0 = *(const float4*)(xp1 + 32);
  float4 nb1 = *(const float4*)(xp1 + 36);
  f16x8 whc[4], wlc[4], whn[4], wln[4];
#pragma unroll
  for (int nt = 0; nt < 4; ++nt) {
    whc[nt] = *(const f16x8*)(whp + nt * 512);
    wlc[nt] = *(const f16x8*)(wlp + nt * 512);
  }

#pragma unroll
  for (int ks = 0; ks < 16; ++ks) {   // fully unrolled; 16 K-steps of 32
    // ---- issue-block: W(ks+1) frags + x(ks+2) tiles ----
    if (ks < 15) {
      const size_t nb_ = (size_t)(ks + 1) * 2048;   // 4*64*8 f16 per k-step
#pragma unroll
      for (int nt = 0; nt < 4; ++nt) {
        whn[nt] = *(const f16x8*)(whp + nb_ + nt * 512);
        wln[nt] = *(const f16x8*)(wlp + nb_ + nt * 512);
      }
    }
    float4 pa0, pa1, pb0, pb1;
    if (ks + 2 < 16) {
      pa0 = *(const float4*)(xp0 + (ks + 2) * 32);
      pa1 = *(const float4*)(xp0 + (ks + 2) * 32 + 4);
      pb0 = *(const float4*)(xp1 + (ks + 2) * 32);
      pb1 = *(const float4*)(xp1 + (ks + 2) * 32 + 4);
    }
    __builtin_amdgcn_sched_barrier(0);   // PIN: loads stay issued above

    // ---- compute-block: current k-step (waitcnt here = vmcnt(~16)) ----
    f16x8 ah, al, bh, bl;
    CVT8(ah, al, ca0, ca1);
    CVT8(bh, bl, cb0, cb1);
#pragma unroll
    for (int nt = 0; nt < 4; ++nt) {
      acc0[nt] = __builtin_amdgcn_mfma_f32_16x16x32_f16(ah, whc[nt], acc0[nt], 0, 0, 0);
      acc1[nt] = __builtin_amdgcn_mfma_f32_16x16x32_f16(bh, whc[nt], acc1[nt], 0, 0, 0);
    }
#pragma unroll
    for (int nt = 0; nt < 4; ++nt) {
      acc0[nt] = __builtin_amdgcn_mfma_f32_16x16x32_f16(ah, wlc[nt], acc0[nt], 0, 0, 0);
      acc1[nt] = __builtin_amdgcn_mfma_f32_16x16x32_f16(bh, wlc[nt], acc1[nt], 0, 0, 0);
    }
#pragma unroll
    for (int nt = 0; nt < 4; ++nt) {
      acc0[nt] = __builtin_amdgcn_mfma_f32_16x16x32_f16(al, whc[nt], acc0[nt], 0, 0, 0);
      acc1[nt] = __builtin_amdgcn_mfma_f32_16x16x32_f16(bl, whc[nt], acc1[nt], 0, 0, 0);
    }
    __builtin_amdgcn_sched_barrier(0);   // PIN: compute stays here

    // rotate (register renames under full unroll)
    ca0 = na0; ca1 = na1; cb0 = nb0; cb1 = nb1;
    na0 = pa0; na1 = pa1; nb0 = pb0; nb1 = pb1;
#pragma unroll
    for (int nt = 0; nt < 4; ++nt) { whc[nt] = whn[nt]; wlc[nt] = wln[nt]; }
  }

  // ---- epilogue to LDS: D col = lane&15, row = (lane>>4)*4 + reg ----
#pragma unroll
  for (int nt = 0; nt < 4; ++nt)
#pragma unroll
    for (int r = 0; r < 4; ++r) {
      plds[wv][lhi * 4 + r][nt * 16 + l15]      = acc0[nt][r];
      plds[wv][16 + lhi * 4 + r][nt * 16 + l15] = acc1[nt][r];
    }
  __syncthreads();

  // ---- 8-seg pairwise tree reduce (rounds 6/9 tree, bit-identical) ----
#pragma unroll
  for (int i = 0; i < 4; ++i) {
    const int elem = tid + i * 512;      // 0..2047
    const int row  = elem >> 6;
    const int col  = elem & 63;
    const float s01 = plds[0][row][col] + plds[1][row][col];
    const float s23 = plds[2][row][col] + plds[3][row][col];
    const float s45 = plds[4][row][col] + plds[5][row][col];
    const float s67 = plds[6][row][col] + plds[7][row][col];
    logit[row][col] = ((s01 + s23) + (s45 + s67));
  }
  __syncthreads();

  // ---- softmax/top-2/renorm (verified rounds 6-14): wave wv rows wv*4..+4 --
  float impacc = 0.f;
#pragma unroll 1
  for (int i = 0; i < 4; ++i) {
    const int rl  = wv * 4 + i;
    const int row = rbase + rl;
    const float lg = logit[rl][lane];

    float m = lg;
#pragma unroll
    for (int d = 1; d < 64; d <<= 1) m = fmaxf(m, __shfl_xor(m, d));
    float p = expf(lg - m);
    float s = p;
#pragma unroll
    for (int d = 1; d < 64; d <<= 1) s += __shfl_xor(s, d);
    const float gate = p / s;
    impacc += gate;

    const unsigned long long key =
        ((unsigned long long)__float_as_uint(gate) << 32) | (unsigned)(63 - lane);
    unsigned long long k1 = key;
#pragma unroll
    for (int d = 1; d < 64; d <<= 1) {
      unsigned long long o = __shfl_xor(k1, d);
      if (o > k1) k1 = o;
    }
    const int e1 = 63 - (int)(k1 & 63ull);
    unsigned long long k2 = (lane == e1) ? 0ull : key;
#pragma unroll
    for (int d = 1; d < 64; d <<= 1) {
      unsigned long long o = __shfl_xor(k2, d);
      if (o > k2) k2 = o;
    }
    const int e2 = 63 - (int)(k2 & 63ull);

    if (lane == 0) {
      const float g1 = __uint_as_float((unsigned)(k1 >> 32));
      const float g2 = __uint_as_float((unsigned)(k2 >> 32));
      const float tt  = expf(g2 - g1);          // g1 >= g2
      const float inv = 1.f / (1.f + tt);
      out[(size_t)row * 2]     = inv;
      out[(size_t)row * 2 + 1] = tt * inv;
      out[(size_t)NROWS * 2 + row * 2]     = (float)e1;
      out[(size_t)NROWS * 2 + row * 2 + 1] = (float)e2;
    }
  }
  simp[wv][lane] = impacc;
  __syncthreads();

  // ---- importance atomics + last-block aux (verified rounds 12/14) ----
  if (tid < NE) {
    const float v = (((simp[0][tid] + simp[1][tid]) + (simp[2][tid] + simp[3][tid])) +
                     ((simp[4][tid] + simp[5][tid]) + (simp[6][tid] + simp[7][tid])));
    atomicAdd(&imp[tid], v);
  }
  __syncthreads();

  if (tid == 0) {
    const unsigned old = atomicAdd(cnt, 1u);
    lastflag = (old == 255u) ? 1 : 0;
  }
  __syncthreads();

  if (lastflag && tid < NE) {
    const float v = atomicAdd(&imp[tid], 0.f);   // device-scope read
    float s = v;
#pragma unroll
    for (int d = 1; d < 64; d <<= 1) s += __shfl_xor(s, d);
    const float mean = s / 64.f;
    const float dv = v - mean;
    float sq = dv * dv;
#pragma unroll
    for (int d = 1; d < 64; d <<= 1) sq += __shfl_xor(sq, d);
    const float stdv = sqrtf(sq / 63.f);  // unbiased (E-1)
    const float r = stdv / (mean + 1e-6f);
    if (tid == 0) out[(size_t)NROWS * 4] = r * r;  // d_out[32768]
  }
}

// ---------------------------------------------------------------------------
extern "C" void kernel_launch(void* const* d_in, const int* in_sizes, int n_in,
                              void* d_out, int out_size, void* d_ws, size_t ws_size,
                              hipStream_t stream) {
  const float* x = (const float*)d_in[0];
  const float* W = (const float*)d_in[1];
  float* out  = (float*)d_out;
  _Float16* Whi = (_Float16*)d_ws;                 // 512 KB
  _Float16* Wlo = Whi + (size_t)NE * NK;           // 512 KB
  float* imp  = (float*)(Wlo + (size_t)NE * NK);   // 64 f32
  unsigned* cnt = (unsigned*)(imp + NE);           // 1 u32

  hipLaunchKernelGGL(k_prep,  dim3(1024), dim3(256), 0, stream, W, Whi, Wlo, imp, cnt);
  hipLaunchKernelGGL(k_fused, dim3(256),  dim3(512), 0, stream, x, Whi, Wlo, out, imp, cnt);
}